// Round 2
// baseline (2454.089 us; speedup 1.0000x reference)
//
#include <hip/hip_runtime.h>

// ---------------------------------------------------------------------------
// S2S RNN (encoder/decoder Elman + output log-softmax) on MI355X.
// fp32 in/out, bf16 operands + fp32 accumulate internally.
//
// Round-8: data-IS-the-flag recurrence. Round-7 post-mortem: the speculative
// plain-load + validate path lost its race ~every step (free-running peers),
// degrading to round-5's poll PLUS a wasted IC round-trip. Fix: poll the
// step-unique h slot DIRECTLY with relaxed agent-scope atomic loads until the
// poison check passes (retry loop IS the design, not a fallback):
//   - producer: one 8B agent-atomic h store, then moves on. No store-drain
//     barrier, no flag publish — store-ack latency leaves the critical path.
//   - consumer: per-THREAD poll of the 128B it stages (one peer's slice);
//     exits as soon as its bytes land. No ballot/flags/fallback kernel.
//   - own slice never round-trips memory: previous-step h kept packed in a
//     register, written straight to LDS; threads whose poll region is the
//     own slot skip polling entirely.
//   - ONE __syncthreads per step (double-buffered LDS h), down from 3.
// Skew self-limits to 1 step (step s needs all of h(s-1)); slots are
// step-unique so there is no overwrite hazard. Correct under any WG->XCD
// placement (atomics are agent-coherent; retry-until-valid).
// Decoder h slots double as states [t][b][j]; final GEMM gathers via mode 3.
// ---------------------------------------------------------------------------

typedef short short8 __attribute__((ext_vector_type(8)));
typedef float floatx4 __attribute__((ext_vector_type(4)));

// ---- ws layout (total need ~138 MB; round-5 path proved >=200 MB exists) ----
#define WS_HENC   0ull                        // 64 MB encoder h slots [s][b][j]
#define WS_HDEC   (64ull << 20)               // 64 MB decoder h == states [t][b][j]
#define WS_WB     (128ull << 20)              // weights/proj region

#define HS_STRIDE 1032  // shorts per LDS row (16B-aligned, +16B pad)

__device__ __forceinline__ float bf2f(unsigned short u) {
  union { unsigned u; float f; } x; x.u = ((unsigned)u) << 16; return x.f;
}
__device__ __forceinline__ unsigned short f2bf(float f) {
  union { float f; unsigned u; } x; x.f = f;
  unsigned r = x.u + 0x7FFFu + ((x.u >> 16) & 1u);  // RNE
  return (unsigned short)(r >> 16);
}
__device__ __forceinline__ unsigned pkminu16(unsigned a, unsigned b) {
  unsigned d;
  asm("v_pk_min_u16 %0, %1, %2" : "=v"(d) : "v"(a), "v"(b));
  return d;
}

// fp32 -> bf16 bulk convert, 4 elems/thread. n multiple of 1024.
__global__ __launch_bounds__(256) void cvt_kernel(
    const float* __restrict__ src, unsigned short* __restrict__ dst, int n)
{
  const int i = (blockIdx.x * 256 + threadIdx.x) * 4;
  if (i >= n) return;
  const float4 v = *(const float4*)(src + i);
  unsigned short o[4] = {f2bf(v.x), f2bf(v.y), f2bf(v.z), f2bf(v.w)};
  *(uint2*)(dst + i) = *(const uint2*)o;
}

// ---------------------------------------------------------------------------
// C[M,N] = gather(A)[M,K] . B[N,K]^T (+ fp32 bias), bf16 operands, fp32 acc.
// 64x64 WG tile, 4 waves, wave tile 16x64 via 16x16x32 bf16 MFMA.
// mode 0: dense rows.
// mode 3: A row m -> Abase + ((m&255)*128 + (m>>8)) * 1024  ([t][b][j] states)
// ---------------------------------------------------------------------------
__global__ __launch_bounds__(256) void gemm_bt_kernel(
    const unsigned short* __restrict__ Abase,
    const int mode,
    const unsigned short* __restrict__ Bmat,
    const float* __restrict__ bias0,
    const float* __restrict__ bias1,
    unsigned short* __restrict__ outp_bf,
    float* __restrict__ outp_f,
    const int K, const int N, const int nbn)
{
  __shared__ unsigned short As[64][264];
  __shared__ unsigned short Bs[64][264];
  __shared__ const unsigned short* rowsrc[64];

  const int tid = threadIdx.x;
  const int lane = tid & 63;
  const int wave = tid >> 6;
  const int bn = blockIdx.x % nbn;
  const int bm = blockIdx.x / nbn;
  const int m0 = bm * 64;
  const int j0 = bn * 64;

  if (tid < 64) {
    const int m = m0 + tid;
    const unsigned short* src;
    if (mode == 0) {
      src = Abase + (size_t)m * K;
    } else {  // mode 3
      src = Abase + ((size_t)(m & 255) * 128 + (m >> 8)) * 1024;
    }
    rowsrc[tid] = src;
  }

  const floatx4 zf = {0.f, 0.f, 0.f, 0.f};
  floatx4 acc0 = zf, acc1 = zf, acc2 = zf, acc3 = zf;

  for (int kc = 0; kc < K; kc += 256) {
    __syncthreads();
#pragma unroll
    for (int i = 0; i < 8; ++i) {
      const int idx = i * 256 + tid;
      const int r = idx >> 5;
      const int c = idx & 31;
      const unsigned short* s = rowsrc[r];
      *(short8*)&As[r][c * 8] = *(const short8*)(s + kc + c * 8);
      *(short8*)&Bs[r][c * 8] =
          *(const short8*)(Bmat + (size_t)(j0 + r) * K + kc + c * 8);
    }
    __syncthreads();
    const int ar = 16 * wave + (lane & 15);
    const int kq = (lane >> 4) * 8;
#pragma unroll
    for (int kk = 0; kk < 8; ++kk) {
      const short8 a = *(const short8*)&As[ar][kk * 32 + kq];
      const short8 bv0 = *(const short8*)&Bs[(lane & 15)][kk * 32 + kq];
      acc0 = __builtin_amdgcn_mfma_f32_16x16x32_bf16(a, bv0, acc0, 0, 0, 0);
      const short8 bv1 = *(const short8*)&Bs[16 + (lane & 15)][kk * 32 + kq];
      acc1 = __builtin_amdgcn_mfma_f32_16x16x32_bf16(a, bv1, acc1, 0, 0, 0);
      const short8 bv2 = *(const short8*)&Bs[32 + (lane & 15)][kk * 32 + kq];
      acc2 = __builtin_amdgcn_mfma_f32_16x16x32_bf16(a, bv2, acc2, 0, 0, 0);
      const short8 bv3 = *(const short8*)&Bs[48 + (lane & 15)][kk * 32 + kq];
      acc3 = __builtin_amdgcn_mfma_f32_16x16x32_bf16(a, bv3, acc3, 0, 0, 0);
    }
  }

  float bs[4] = {0.f, 0.f, 0.f, 0.f};
  if (bias0) {
#pragma unroll
    for (int nt = 0; nt < 4; ++nt) {
      const int jj = j0 + nt * 16 + (lane & 15);
      bs[nt] = bias0[jj] + bias1[jj];
    }
  }
  __syncthreads();
  const int rbase = 16 * wave + (lane >> 4) * 4;
  const int cl = lane & 15;

  if (outp_bf) {
#pragma unroll
    for (int i = 0; i < 4; ++i) {
      As[rbase + i][cl]      = f2bf(acc0[i] + bs[0]);
      As[rbase + i][16 + cl] = f2bf(acc1[i] + bs[1]);
      As[rbase + i][32 + cl] = f2bf(acc2[i] + bs[2]);
      As[rbase + i][48 + cl] = f2bf(acc3[i] + bs[3]);
    }
    __syncthreads();
#pragma unroll
    for (int i = 0; i < 2; ++i) {
      const int idx = i * 256 + tid;
      const int r = idx >> 3;
      const int c = idx & 7;
      *(short8*)(outp_bf + (size_t)(m0 + r) * N + j0 + c * 8) =
          *(const short8*)&As[r][c * 8];
    }
  } else {
    float (*Asf)[66] = (float(*)[66]) & As[0][0];
#pragma unroll
    for (int i = 0; i < 4; ++i) {
      Asf[rbase + i][cl]      = acc0[i] + bs[0];
      Asf[rbase + i][16 + cl] = acc1[i] + bs[1];
      Asf[rbase + i][32 + cl] = acc2[i] + bs[2];
      Asf[rbase + i][48 + cl] = acc3[i] + bs[3];
    }
    __syncthreads();
#pragma unroll
    for (int i = 0; i < 4; ++i) {
      const int idx = i * 256 + tid;
      const int r = idx >> 4;
      const int c = idx & 15;
      *(float4*)(outp_f + (size_t)(m0 + r) * N + j0 + c * 4) =
          *(const float4*)&Asf[r][c * 4];
    }
  }
}

// ---------------------------------------------------------------------------
// Round-8 recurrence. 128 WGs x 256 thr; group g = blockIdx&7 owns batch rows
// [16g,16g+16); 16 WGs/group cover 1024 cols (64/WG, 16/wave).
// Per-thread data-poll of step-unique slots; no flags, no fallback kernel.
// ---------------------------------------------------------------------------
__global__ __launch_bounds__(256) void rnn_scan4_kernel(
    const unsigned short* __restrict__ WhhE,
    const unsigned short* __restrict__ WhhD,
    const unsigned short* __restrict__ projE,
    const unsigned short* __restrict__ projD,
    const float* __restrict__ decBih,
    const float* __restrict__ decBhh,
    const int* __restrict__ intoks,    // inputs  [128][256] int32
    const int* __restrict__ outtoks,   // outputs [128][256] int32
    unsigned short* __restrict__ henc, // [256][128][1024] encoder h slots
    unsigned short* __restrict__ hdec) // [256][128][1024] decoder h == states
{
  __shared__ unsigned short hs[2 * 16 * HS_STRIDE];  // double-buffered
  __shared__ int toks[16 * 257];

  const int tid = threadIdx.x;
  const int lane = tid & 63;
  const int wave = tid >> 6;
  const int g = blockIdx.x & 7;
  const int slot = blockIdx.x >> 3;
  const int b0 = g * 16;
  const int q = lane >> 4;
  const int cl = lane & 15;
  const int jwb = slot * 64 + wave * 16;  // wave's 16-column base
  const int jq4 = jwb + q * 4;            // this thread's 4 output columns
  // This thread stages j-block (tid&127) (8 cols x 8 of 16 b-rows = 128B),
  // i.e. data produced by WG 'slot' = (tid&127)>>3 of this group. If that is
  // our own WG, the data never needs to round-trip memory (kept in obp).
  const bool own = (((tid & 127) >> 3) == slot);

  short8 w[32];  // Whh[jwb+cl][0:1024] A-fragments — 128 VGPRs
  const floatx4 zf = {0.f, 0.f, 0.f, 0.f};
  unsigned long long obp = 0;  // packed own h(s-1): rows (b0+cl), cols jq4..+3

  for (int phase = 0; phase < 2; ++phase) {
    const unsigned short* Whh = phase ? WhhD : WhhE;
    const unsigned short* proj = phase ? projD : projE;
    const int* gt = phase ? outtoks : intoks;
    {
      const unsigned short* wp = Whh + (size_t)(jwb + cl) * 1024 + q * 8;
#pragma unroll
      for (int kk = 0; kk < 32; ++kk) w[kk] = *(const short8*)(wp + kk * 32);
    }
    float xb[4] = {0.f, 0.f, 0.f, 0.f};
    if (phase) {  // decoder t==0 input is zero -> xp = bih+bhh (fp32, exact)
#pragma unroll
      for (int i = 0; i < 4; ++i) xb[i] = decBih[jq4 + i] + decBhh[jq4 + i];
    }
    // stage this phase's token ids (16 rows x 256 steps) into LDS
    __syncthreads();
#pragma unroll
    for (int i = 0; i < 16; ++i) {
      const int idx = i * 256 + tid;
      toks[(idx >> 8) * 257 + (idx & 255)] =
          gt[(size_t)(b0 + (idx >> 8)) * 256 + (idx & 255)];
    }
    __syncthreads();

    for (int t = 0; t < 256; ++t) {
      const int s = phase * 256 + t;
      // xp gather (issued early; latency hides under the h poll)
      float xpf[4];
      {
        const int tt = phase ? (t > 0 ? t - 1 : 0) : t;
        const int tok = toks[cl * 257 + tt];
        const uint2 xr = *(const uint2*)(proj + (size_t)tok * 1024 + jq4);
        const unsigned short* xs = (const unsigned short*)&xr;
#pragma unroll
        for (int i = 0; i < 4; ++i) xpf[i] = bf2f(xs[i]);
        if (phase && t == 0) {
#pragma unroll
          for (int i = 0; i < 4; ++i) xpf[i] = xb[i];
        }
      }

      unsigned short* hsb = hs + (s & 1) * (16 * HS_STRIDE);
      if (s > 0) {
        const unsigned short* hprev =
            (s <= 256 ? henc + (size_t)(s - 1) * 131072
                      : hdec + (size_t)(s - 257) * 131072) + b0 * 1024;
        if (!own) {
          short8 tmp[8];
          for (;;) {
            // 16 relaxed agent-scope 8B loads, issued in parallel (one
            // latency per retry); coherent regardless of XCD placement.
#pragma unroll
            for (int c = 0; c < 8; ++c) {
              const unsigned long long* p =
                  (const unsigned long long*)(hprev + (c * 256 + tid) * 8);
              union { unsigned long long u[2]; short8 s8; } v;
              v.u[0] = __hip_atomic_load(p, __ATOMIC_RELAXED,
                                         __HIP_MEMORY_SCOPE_AGENT);
              v.u[1] = __hip_atomic_load(p + 1, __ATOMIC_RELAXED,
                                         __HIP_MEMORY_SCOPE_AGENT);
              tmp[c] = v.s8;
            }
            // poison-validity: any short == 0xAAAA -> producer not done yet
            const unsigned* du = (const unsigned*)tmp;
            unsigned m0v = 0xFFFFFFFFu, m1v = 0xFFFFFFFFu;
            unsigned m2v = 0xFFFFFFFFu, m3v = 0xFFFFFFFFu;
#pragma unroll
            for (int i = 0; i < 8; ++i) {
              m0v = pkminu16(m0v, du[4 * i + 0] ^ 0xAAAAAAAAu);
              m1v = pkminu16(m1v, du[4 * i + 1] ^ 0xAAAAAAAAu);
              m2v = pkminu16(m2v, du[4 * i + 2] ^ 0xAAAAAAAAu);
              m3v = pkminu16(m3v, du[4 * i + 3] ^ 0xAAAAAAAAu);
            }
            const unsigned mm = pkminu16(pkminu16(m0v, m1v), pkminu16(m2v, m3v));
            const unsigned hz = (mm - 0x00010001u) & ~mm & 0x80008000u;
            if (hz == 0u) {
#pragma unroll
              for (int c = 0; c < 8; ++c) {
                const int gg = c * 256 + tid;
                *(short8*)&hsb[(gg >> 7) * HS_STRIDE + (gg & 127) * 8] = tmp[c];
              }
              break;
            }
            __builtin_amdgcn_s_sleep(1);
          }
        }
        // own slice straight from registers (no memory round-trip)
        *(unsigned long long*)&hsb[cl * HS_STRIDE + jq4] = obp;
      }
      __syncthreads();  // hs ready (also orders 2-steps-apart buffer reuse)

      floatx4 acc0 = zf, acc1 = zf, acc2 = zf, acc3 = zf;
      if (s > 0) {
        // swapped operands: D[j_local][b_local]; thread owns (b0+cl, jq4..+3)
        const unsigned short* hrow = &hsb[cl * HS_STRIDE + q * 8];
#pragma unroll
        for (int kk = 0; kk < 32; kk += 4) {
          const short8 a0 = *(const short8*)(hrow + (kk + 0) * 32);
          const short8 a1 = *(const short8*)(hrow + (kk + 1) * 32);
          const short8 a2 = *(const short8*)(hrow + (kk + 2) * 32);
          const short8 a3 = *(const short8*)(hrow + (kk + 3) * 32);
          acc0 = __builtin_amdgcn_mfma_f32_16x16x32_bf16(w[kk + 0], a0, acc0, 0, 0, 0);
          acc1 = __builtin_amdgcn_mfma_f32_16x16x32_bf16(w[kk + 1], a1, acc1, 0, 0, 0);
          acc2 = __builtin_amdgcn_mfma_f32_16x16x32_bf16(w[kk + 2], a2, acc2, 0, 0, 0);
          acc3 = __builtin_amdgcn_mfma_f32_16x16x32_bf16(w[kk + 3], a3, acc3, 0, 0, 0);
        }
      }
      unsigned short ob[4];
#pragma unroll
      for (int i = 0; i < 4; ++i) {
        const float pre = acc0[i] + acc1[i] + acc2[i] + acc3[i] + xpf[i];
        const float e = __expf(2.f * pre);
        ob[i] = f2bf(1.f - 2.f / (e + 1.f));  // tanh
      }
      obp = *(const unsigned long long*)ob;
      unsigned short* hw =
          phase ? hdec + (size_t)t * 131072 : henc + (size_t)s * 131072;
      // one 8B agent-scope atomic store; no drain, no flag — the data is the
      // flag (consumers poll it). Producer moves straight to its next poll.
      __hip_atomic_store(
          (unsigned long long*)(hw + (size_t)(b0 + cl) * 1024 + jq4),
          obp, __ATOMIC_RELAXED, __HIP_MEMORY_SCOPE_AGENT);
    }
  }
}

// ---------------------------------------------------------------------------
// Rowwise log_softmax over V=512 with fp32 bias, fp32 in-place on d_out.
// ---------------------------------------------------------------------------
__global__ __launch_bounds__(256) void logsoftmax_kernel(
    float* __restrict__ logits, const float* __restrict__ outb)
{
  const int row = blockIdx.x * 4 + (threadIdx.x >> 6);
  const int lane = threadIdx.x & 63;
  float* rp = logits + (size_t)row * 512 + lane * 8;
  const float4 a0 = *(const float4*)rp;
  const float4 a1 = *(const float4*)(rp + 4);
  const float4 b0 = *(const float4*)(outb + lane * 8);
  const float4 b1 = *(const float4*)(outb + lane * 8 + 4);
  float v[8] = {a0.x + b0.x, a0.y + b0.y, a0.z + b0.z, a0.w + b0.w,
                a1.x + b1.x, a1.y + b1.y, a1.z + b1.z, a1.w + b1.w};
  float mx = v[0];
#pragma unroll
  for (int i = 1; i < 8; ++i) mx = fmaxf(mx, v[i]);
#pragma unroll
  for (int m = 1; m < 64; m <<= 1) mx = fmaxf(mx, __shfl_xor(mx, m, 64));
  float sum = 0.f;
#pragma unroll
  for (int i = 0; i < 8; ++i) sum += __expf(v[i] - mx);
#pragma unroll
  for (int m = 1; m < 64; m <<= 1) sum += __shfl_xor(sum, m, 64);
  const float lse = mx + __logf(sum);
  float4 o0 = {v[0] - lse, v[1] - lse, v[2] - lse, v[3] - lse};
  float4 o1 = {v[4] - lse, v[5] - lse, v[6] - lse, v[7] - lse};
  *(float4*)rp = o0;
  *(float4*)(rp + 4) = o1;
}

extern "C" void kernel_launch(void* const* d_in, const int* in_sizes, int n_in,
                              void* d_out, int out_size, void* d_ws, size_t ws_size,
                              hipStream_t stream)
{
  const int* inputs  = (const int*)d_in[0];
  const int* outputs = (const int*)d_in[1];
  const float* emb    = (const float*)d_in[2];
  const float* encWih = (const float*)d_in[3];
  const float* encWhh = (const float*)d_in[4];
  const float* encBih = (const float*)d_in[5];
  const float* encBhh = (const float*)d_in[6];
  const float* decWih = (const float*)d_in[7];
  const float* decWhh = (const float*)d_in[8];
  const float* decBih = (const float*)d_in[9];
  const float* decBhh = (const float*)d_in[10];
  const float* outW   = (const float*)d_in[11];
  const float* outB   = (const float*)d_in[12];

  char* ws = (char*)d_ws;
  unsigned short* henc = (unsigned short*)(ws + WS_HENC);
  unsigned short* hdec = (unsigned short*)(ws + WS_HDEC);  // == states [t][b][j]
  char* wb = ws + WS_WB;
  unsigned short* embB  = (unsigned short*)(wb + 0);
  unsigned short* eWihB = (unsigned short*)(wb + (512ull << 10));
  unsigned short* dWihB = (unsigned short*)(wb + (1ull << 20));
  unsigned short* eWhhB = (unsigned short*)(wb + (2ull << 20));
  unsigned short* dWhhB = (unsigned short*)(wb + (4ull << 20));
  unsigned short* outWB = (unsigned short*)(wb + (6ull << 20));
  unsigned short* projE = (unsigned short*)(wb + (7ull << 20));
  unsigned short* projD = (unsigned short*)(wb + (8ull << 20));
  float* logits = (float*)d_out;

  cvt_kernel<<<128, 256, 0, stream>>>(emb, embB, 512 * 256);
  cvt_kernel<<<256, 256, 0, stream>>>(encWih, eWihB, 1024 * 256);
  cvt_kernel<<<256, 256, 0, stream>>>(decWih, dWihB, 1024 * 256);
  cvt_kernel<<<1024, 256, 0, stream>>>(encWhh, eWhhB, 1024 * 1024);
  cvt_kernel<<<1024, 256, 0, stream>>>(decWhh, dWhhB, 1024 * 1024);
  cvt_kernel<<<512, 256, 0, stream>>>(outW, outWB, 512 * 1024);

  // projected-vocab tables: proj[v] = emb[v] @ Wih^T + bih + bhh  (512x1024)
  gemm_bt_kernel<<<128, 256, 0, stream>>>(embB, 0, eWihB, encBih, encBhh,
                                          projE, nullptr, 256, 1024, 16);
  gemm_bt_kernel<<<128, 256, 0, stream>>>(embB, 0, dWihB, decBih, decBhh,
                                          projD, nullptr, 256, 1024, 16);

  rnn_scan4_kernel<<<128, 256, 0, stream>>>(eWhhB, dWhhB, projE, projD,
                                            decBih, decBhh, inputs, outputs,
                                            henc, hdec);

  gemm_bt_kernel<<<4096, 256, 0, stream>>>(hdec, 3, outWB, nullptr, nullptr,
                                           nullptr, logits, 1024, 512, 8);
  logsoftmax_kernel<<<8192, 256, 0, stream>>>(logits, outB);
}

// Round 3
// 2028.839 us; speedup vs baseline: 1.2096x; 1.2096x over previous
//
#include <hip/hip_runtime.h>

// ---------------------------------------------------------------------------
// S2S RNN (encoder/decoder Elman + output log-softmax) on MI355X.
// fp32 in/out, bf16 operands + fp32 accumulate internally.
//
// Round-9: IC-hot WINDOW + poison-validity data-poll.
// Post-mortem of rounds 7/8: step-unique slots put cold HBM-resident poisoned
// lines on the critical path (producer store = write-allocate HBM fetch,
// early consumer poll = HBM miss). Round-5's reused ping-pong was IC-hot —
// that's why it won. This round keeps the 2-round-trip data-is-the-flag
// handshake but runs it on a reused 8-slot window (2 MB, IC-resident):
//   - slot(s) = s mod 8; producer: one 8B agent-atomic store, moves on.
//   - consumer: per-thread poll (relaxed agent loads) until poison check
//     passes. No flags, no fallback kernel.
//   - re-poison: at end of step s (post-barrier), each producer thread
//     agent-stores 0xAAAA over the region it produced at s-2. Safe by
//     induction: validating slot s-1 proves peers produced s-1, hence fully
//     consumed s-2. Poison retires >=5 steps before slot reuse at s+6.
//   - anti-hang fixup: produced h shorts equal to 0xAAAA flip to 0xAAAB
//     (1 ulp, within tolerance) so validity can't spin forever.
//   - decoder h ALSO streams to states[t][b][j] via NONTEMPORAL stores.
//   - step barrier = raw s_barrier + lgkmcnt(0) only (sched_barrier-pinned):
//     states/poison/window stores are never vmcnt-drained on the hot path.
// Final GEMM gathers states via mode 3. ws need ~75 MB.
// ---------------------------------------------------------------------------

typedef short short8 __attribute__((ext_vector_type(8)));
typedef float floatx4 __attribute__((ext_vector_type(4)));

// ---- ws layout (~75 MB) ----
#define WS_WIN    0ull                        // 2 MB: [8][128][1024] bf16 window
#define WS_STATES (2ull << 20)                // 64 MB: [256][128][1024] bf16
#define WS_WB     (66ull << 20)               // weights/proj region

#define HS_STRIDE 1032  // shorts per LDS row (16B-aligned, +16B pad)

__device__ __forceinline__ float bf2f(unsigned short u) {
  union { unsigned u; float f; } x; x.u = ((unsigned)u) << 16; return x.f;
}
__device__ __forceinline__ unsigned short f2bf(float f) {
  union { float f; unsigned u; } x; x.f = f;
  unsigned r = x.u + 0x7FFFu + ((x.u >> 16) & 1u);  // RNE
  return (unsigned short)(r >> 16);
}
__device__ __forceinline__ unsigned pkminu16(unsigned a, unsigned b) {
  unsigned d;
  asm("v_pk_min_u16 %0, %1, %2" : "=v"(d) : "v"(a), "v"(b));
  return d;
}

// fp32 -> bf16 bulk convert, 4 elems/thread. n multiple of 1024.
__global__ __launch_bounds__(256) void cvt_kernel(
    const float* __restrict__ src, unsigned short* __restrict__ dst, int n)
{
  const int i = (blockIdx.x * 256 + threadIdx.x) * 4;
  if (i >= n) return;
  const float4 v = *(const float4*)(src + i);
  unsigned short o[4] = {f2bf(v.x), f2bf(v.y), f2bf(v.z), f2bf(v.w)};
  *(uint2*)(dst + i) = *(const uint2*)o;
}

// ---------------------------------------------------------------------------
// C[M,N] = gather(A)[M,K] . B[N,K]^T (+ fp32 bias), bf16 operands, fp32 acc.
// 64x64 WG tile, 4 waves, wave tile 16x64 via 16x16x32 bf16 MFMA.
// mode 0: dense rows.
// mode 3: A row m -> Abase + ((m&255)*128 + (m>>8)) * 1024  ([t][b][j] states)
// ---------------------------------------------------------------------------
__global__ __launch_bounds__(256) void gemm_bt_kernel(
    const unsigned short* __restrict__ Abase,
    const int mode,
    const unsigned short* __restrict__ Bmat,
    const float* __restrict__ bias0,
    const float* __restrict__ bias1,
    unsigned short* __restrict__ outp_bf,
    float* __restrict__ outp_f,
    const int K, const int N, const int nbn)
{
  __shared__ unsigned short As[64][264];
  __shared__ unsigned short Bs[64][264];
  __shared__ const unsigned short* rowsrc[64];

  const int tid = threadIdx.x;
  const int lane = tid & 63;
  const int wave = tid >> 6;
  const int bn = blockIdx.x % nbn;
  const int bm = blockIdx.x / nbn;
  const int m0 = bm * 64;
  const int j0 = bn * 64;

  if (tid < 64) {
    const int m = m0 + tid;
    const unsigned short* src;
    if (mode == 0) {
      src = Abase + (size_t)m * K;
    } else {  // mode 3
      src = Abase + ((size_t)(m & 255) * 128 + (m >> 8)) * 1024;
    }
    rowsrc[tid] = src;
  }

  const floatx4 zf = {0.f, 0.f, 0.f, 0.f};
  floatx4 acc0 = zf, acc1 = zf, acc2 = zf, acc3 = zf;

  for (int kc = 0; kc < K; kc += 256) {
    __syncthreads();
#pragma unroll
    for (int i = 0; i < 8; ++i) {
      const int idx = i * 256 + tid;
      const int r = idx >> 5;
      const int c = idx & 31;
      const unsigned short* s = rowsrc[r];
      *(short8*)&As[r][c * 8] = *(const short8*)(s + kc + c * 8);
      *(short8*)&Bs[r][c * 8] =
          *(const short8*)(Bmat + (size_t)(j0 + r) * K + kc + c * 8);
    }
    __syncthreads();
    const int ar = 16 * wave + (lane & 15);
    const int kq = (lane >> 4) * 8;
#pragma unroll
    for (int kk = 0; kk < 8; ++kk) {
      const short8 a = *(const short8*)&As[ar][kk * 32 + kq];
      const short8 bv0 = *(const short8*)&Bs[(lane & 15)][kk * 32 + kq];
      acc0 = __builtin_amdgcn_mfma_f32_16x16x32_bf16(a, bv0, acc0, 0, 0, 0);
      const short8 bv1 = *(const short8*)&Bs[16 + (lane & 15)][kk * 32 + kq];
      acc1 = __builtin_amdgcn_mfma_f32_16x16x32_bf16(a, bv1, acc1, 0, 0, 0);
      const short8 bv2 = *(const short8*)&Bs[32 + (lane & 15)][kk * 32 + kq];
      acc2 = __builtin_amdgcn_mfma_f32_16x16x32_bf16(a, bv2, acc2, 0, 0, 0);
      const short8 bv3 = *(const short8*)&Bs[48 + (lane & 15)][kk * 32 + kq];
      acc3 = __builtin_amdgcn_mfma_f32_16x16x32_bf16(a, bv3, acc3, 0, 0, 0);
    }
  }

  float bs[4] = {0.f, 0.f, 0.f, 0.f};
  if (bias0) {
#pragma unroll
    for (int nt = 0; nt < 4; ++nt) {
      const int jj = j0 + nt * 16 + (lane & 15);
      bs[nt] = bias0[jj] + bias1[jj];
    }
  }
  __syncthreads();
  const int rbase = 16 * wave + (lane >> 4) * 4;
  const int cl = lane & 15;

  if (outp_bf) {
#pragma unroll
    for (int i = 0; i < 4; ++i) {
      As[rbase + i][cl]      = f2bf(acc0[i] + bs[0]);
      As[rbase + i][16 + cl] = f2bf(acc1[i] + bs[1]);
      As[rbase + i][32 + cl] = f2bf(acc2[i] + bs[2]);
      As[rbase + i][48 + cl] = f2bf(acc3[i] + bs[3]);
    }
    __syncthreads();
#pragma unroll
    for (int i = 0; i < 2; ++i) {
      const int idx = i * 256 + tid;
      const int r = idx >> 3;
      const int c = idx & 7;
      *(short8*)(outp_bf + (size_t)(m0 + r) * N + j0 + c * 8) =
          *(const short8*)&As[r][c * 8];
    }
  } else {
    float (*Asf)[66] = (float(*)[66]) & As[0][0];
#pragma unroll
    for (int i = 0; i < 4; ++i) {
      Asf[rbase + i][cl]      = acc0[i] + bs[0];
      Asf[rbase + i][16 + cl] = acc1[i] + bs[1];
      Asf[rbase + i][32 + cl] = acc2[i] + bs[2];
      Asf[rbase + i][48 + cl] = acc3[i] + bs[3];
    }
    __syncthreads();
#pragma unroll
    for (int i = 0; i < 4; ++i) {
      const int idx = i * 256 + tid;
      const int r = idx >> 4;
      const int c = idx & 15;
      *(float4*)(outp_f + (size_t)(m0 + r) * N + j0 + c * 4) =
          *(const float4*)&Asf[r][c * 4];
    }
  }
}

// ---------------------------------------------------------------------------
// Round-9 recurrence. 128 WGs x 256 thr; group g = blockIdx&7 owns batch rows
// [16g,16g+16); 16 WGs/group cover 1024 cols (64/WG, 16/wave).
// IC-hot 8-slot window, per-thread data-poll, re-poison, raw lgkm barrier.
// ---------------------------------------------------------------------------
__global__ __launch_bounds__(256) void rnn_scan5_kernel(
    const unsigned short* __restrict__ WhhE,
    const unsigned short* __restrict__ WhhD,
    const unsigned short* __restrict__ projE,
    const unsigned short* __restrict__ projD,
    const float* __restrict__ decBih,
    const float* __restrict__ decBhh,
    const int* __restrict__ intoks,     // inputs  [128][256] int32
    const int* __restrict__ outtoks,    // outputs [128][256] int32
    unsigned short* __restrict__ win,   // [8][128][1024] window slots
    unsigned short* __restrict__ states)// [256][128][1024] decoder states
{
  __shared__ unsigned short hs[2 * 16 * HS_STRIDE];  // double-buffered
  __shared__ int toks[16 * 257];

  const int tid = threadIdx.x;
  const int lane = tid & 63;
  const int wave = tid >> 6;
  const int g = blockIdx.x & 7;
  const int slot = blockIdx.x >> 3;
  const int b0 = g * 16;
  const int q = lane >> 4;
  const int cl = lane & 15;
  const int jwb = slot * 64 + wave * 16;  // wave's 16-column base
  const int jq4 = jwb + q * 4;            // this thread's 4 output columns
  // This thread stages col-slice (tid&127)*8..+8 across 8 b-rows (128B),
  // produced by WG (tid&127)>>3 of this group. Own WG's data stays in obp.
  const bool own = (((tid & 127) >> 3) == slot);
  // This thread's production address within a slot:
  const size_t prodoff = (size_t)(b0 + cl) * 1024 + jq4;

  short8 w[32];  // Whh[jwb+cl][0:1024] A-fragments — 128 VGPRs
  const floatx4 zf = {0.f, 0.f, 0.f, 0.f};
  unsigned long long obp = 0;  // packed own h(s-1): row b0+cl, cols jq4..+3

  for (int phase = 0; phase < 2; ++phase) {
    const unsigned short* Whh = phase ? WhhD : WhhE;
    const unsigned short* proj = phase ? projD : projE;
    const int* gt = phase ? outtoks : intoks;
    {
      const unsigned short* wp = Whh + (size_t)(jwb + cl) * 1024 + q * 8;
#pragma unroll
      for (int kk = 0; kk < 32; ++kk) w[kk] = *(const short8*)(wp + kk * 32);
    }
    float xb[4] = {0.f, 0.f, 0.f, 0.f};
    if (phase) {  // decoder t==0 input is zero -> xp = bih+bhh (fp32, exact)
#pragma unroll
      for (int i = 0; i < 4; ++i) xb[i] = decBih[jq4 + i] + decBhh[jq4 + i];
    }
    // stage this phase's token ids (16 rows x 256 steps) into LDS
    __syncthreads();
#pragma unroll
    for (int i = 0; i < 16; ++i) {
      const int idx = i * 256 + tid;
      toks[(idx >> 8) * 257 + (idx & 255)] =
          gt[(size_t)(b0 + (idx >> 8)) * 256 + (idx & 255)];
    }
    __syncthreads();

    for (int t = 0; t < 256; ++t) {
      const int s = phase * 256 + t;
      // xp gather (issued early; latency hides under the h poll)
      float xpf[4];
      {
        const int tt = phase ? (t > 0 ? t - 1 : 0) : t;
        const int tok = toks[cl * 257 + tt];
        const uint2 xr = *(const uint2*)(proj + (size_t)tok * 1024 + jq4);
        const unsigned short* xs = (const unsigned short*)&xr;
#pragma unroll
        for (int i = 0; i < 4; ++i) xpf[i] = bf2f(xs[i]);
        if (phase && t == 0) {
#pragma unroll
          for (int i = 0; i < 4; ++i) xpf[i] = xb[i];
        }
      }

      unsigned short* hsb = hs + (s & 1) * (16 * HS_STRIDE);
      if (s > 0) {
        const unsigned short* hprev =
            win + (size_t)((s - 1) & 7) * 131072 + b0 * 1024;
        if (!own) {
          short8 tmp[8];
          for (;;) {
            // 16 relaxed agent-scope 8B loads of IC-HOT window lines.
#pragma unroll
            for (int c = 0; c < 8; ++c) {
              const unsigned long long* p =
                  (const unsigned long long*)(hprev + (c * 256 + tid) * 8);
              union { unsigned long long u[2]; short8 s8; } v;
              v.u[0] = __hip_atomic_load(p, __ATOMIC_RELAXED,
                                         __HIP_MEMORY_SCOPE_AGENT);
              v.u[1] = __hip_atomic_load(p + 1, __ATOMIC_RELAXED,
                                         __HIP_MEMORY_SCOPE_AGENT);
              tmp[c] = v.s8;
            }
            // poison-validity: any short == 0xAAAA -> producer not done yet
            const unsigned* du = (const unsigned*)tmp;
            unsigned m0v = 0xFFFFFFFFu, m1v = 0xFFFFFFFFu;
            unsigned m2v = 0xFFFFFFFFu, m3v = 0xFFFFFFFFu;
#pragma unroll
            for (int i = 0; i < 8; ++i) {
              m0v = pkminu16(m0v, du[4 * i + 0] ^ 0xAAAAAAAAu);
              m1v = pkminu16(m1v, du[4 * i + 1] ^ 0xAAAAAAAAu);
              m2v = pkminu16(m2v, du[4 * i + 2] ^ 0xAAAAAAAAu);
              m3v = pkminu16(m3v, du[4 * i + 3] ^ 0xAAAAAAAAu);
            }
            const unsigned mm = pkminu16(pkminu16(m0v, m1v), pkminu16(m2v, m3v));
            const unsigned hz = (mm - 0x00010001u) & ~mm & 0x80008000u;
            if (hz == 0u) {
#pragma unroll
              for (int c = 0; c < 8; ++c) {
                const int gg = c * 256 + tid;
                *(short8*)&hsb[(gg >> 7) * HS_STRIDE + (gg & 127) * 8] = tmp[c];
              }
              break;
            }
            __builtin_amdgcn_s_sleep(1);
          }
        }
        // own slice straight from registers (no memory round-trip)
        *(unsigned long long*)&hsb[cl * HS_STRIDE + jq4] = obp;
      }
      // Raw barrier: drain LDS writes only; window/states/poison stores stay
      // in flight (never vmcnt-drained on the critical path).
      __builtin_amdgcn_sched_barrier(0);
      asm volatile("s_waitcnt lgkmcnt(0)" ::: "memory");
      __builtin_amdgcn_s_barrier();
      __builtin_amdgcn_sched_barrier(0);

      floatx4 acc0 = zf, acc1 = zf, acc2 = zf, acc3 = zf;
      if (s > 0) {
        // swapped operands: D[j_local][b_local]; thread owns (b0+cl, jq4..+3)
        const unsigned short* hrow = &hsb[cl * HS_STRIDE + q * 8];
#pragma unroll
        for (int kk = 0; kk < 32; kk += 4) {
          const short8 a0 = *(const short8*)(hrow + (kk + 0) * 32);
          const short8 a1 = *(const short8*)(hrow + (kk + 1) * 32);
          const short8 a2 = *(const short8*)(hrow + (kk + 2) * 32);
          const short8 a3 = *(const short8*)(hrow + (kk + 3) * 32);
          acc0 = __builtin_amdgcn_mfma_f32_16x16x32_bf16(w[kk + 0], a0, acc0, 0, 0, 0);
          acc1 = __builtin_amdgcn_mfma_f32_16x16x32_bf16(w[kk + 1], a1, acc1, 0, 0, 0);
          acc2 = __builtin_amdgcn_mfma_f32_16x16x32_bf16(w[kk + 2], a2, acc2, 0, 0, 0);
          acc3 = __builtin_amdgcn_mfma_f32_16x16x32_bf16(w[kk + 3], a3, acc3, 0, 0, 0);
        }
      }
      unsigned short ob[4];
#pragma unroll
      for (int i = 0; i < 4; ++i) {
        const float pre = acc0[i] + acc1[i] + acc2[i] + acc3[i] + xpf[i];
        const float e = __expf(2.f * pre);
        ob[i] = f2bf(1.f - 2.f / (e + 1.f));  // tanh
        if (ob[i] == 0xAAAAu) ob[i] = 0xAAABu;  // anti-hang: 1-ulp fixup
      }
      obp = *(const unsigned long long*)ob;
      // window store first (critical handshake), IC-hot line.
      __hip_atomic_store(
          (unsigned long long*)(win + (size_t)(s & 7) * 131072 + prodoff),
          obp, __ATOMIC_RELAXED, __HIP_MEMORY_SCOPE_AGENT);
      // decoder states stream: nontemporal, background (never drained here).
      if (phase) {
        __builtin_nontemporal_store(
            obp, (unsigned long long*)(states + (size_t)t * 131072 + prodoff));
      }
      // re-poison slot s-2 (post-barrier => all peers consumed it; retires
      // >=5 steps before reuse at s+6).
      if (s >= 2) {
        __hip_atomic_store(
            (unsigned long long*)(win + (size_t)((s - 2) & 7) * 131072 + prodoff),
            0xAAAAAAAAAAAAAAAAull, __ATOMIC_RELAXED, __HIP_MEMORY_SCOPE_AGENT);
      }
    }
  }
}

// ---------------------------------------------------------------------------
// Rowwise log_softmax over V=512 with fp32 bias, fp32 in-place on d_out.
// ---------------------------------------------------------------------------
__global__ __launch_bounds__(256) void logsoftmax_kernel(
    float* __restrict__ logits, const float* __restrict__ outb)
{
  const int row = blockIdx.x * 4 + (threadIdx.x >> 6);
  const int lane = threadIdx.x & 63;
  float* rp = logits + (size_t)row * 512 + lane * 8;
  const float4 a0 = *(const float4*)rp;
  const float4 a1 = *(const float4*)(rp + 4);
  const float4 b0 = *(const float4*)(outb + lane * 8);
  const float4 b1 = *(const float4*)(outb + lane * 8 + 4);
  float v[8] = {a0.x + b0.x, a0.y + b0.y, a0.z + b0.z, a0.w + b0.w,
                a1.x + b1.x, a1.y + b1.y, a1.z + b1.z, a1.w + b1.w};
  float mx = v[0];
#pragma unroll
  for (int i = 1; i < 8; ++i) mx = fmaxf(mx, v[i]);
#pragma unroll
  for (int m = 1; m < 64; m <<= 1) mx = fmaxf(mx, __shfl_xor(mx, m, 64));
  float sum = 0.f;
#pragma unroll
  for (int i = 0; i < 8; ++i) sum += __expf(v[i] - mx);
#pragma unroll
  for (int m = 1; m < 64; m <<= 1) sum += __shfl_xor(sum, m, 64);
  const float lse = mx + __logf(sum);
  float4 o0 = {v[0] - lse, v[1] - lse, v[2] - lse, v[3] - lse};
  float4 o1 = {v[4] - lse, v[5] - lse, v[6] - lse, v[7] - lse};
  *(float4*)rp = o0;
  *(float4*)(rp + 4) = o1;
}

extern "C" void kernel_launch(void* const* d_in, const int* in_sizes, int n_in,
                              void* d_out, int out_size, void* d_ws, size_t ws_size,
                              hipStream_t stream)
{
  const int* inputs  = (const int*)d_in[0];
  const int* outputs = (const int*)d_in[1];
  const float* emb    = (const float*)d_in[2];
  const float* encWih = (const float*)d_in[3];
  const float* encWhh = (const float*)d_in[4];
  const float* encBih = (const float*)d_in[5];
  const float* encBhh = (const float*)d_in[6];
  const float* decWih = (const float*)d_in[7];
  const float* decWhh = (const float*)d_in[8];
  const float* decBih = (const float*)d_in[9];
  const float* decBhh = (const float*)d_in[10];
  const float* outW   = (const float*)d_in[11];
  const float* outB   = (const float*)d_in[12];

  char* ws = (char*)d_ws;
  unsigned short* win    = (unsigned short*)(ws + WS_WIN);
  unsigned short* states = (unsigned short*)(ws + WS_STATES);
  char* wb = ws + WS_WB;
  unsigned short* embB  = (unsigned short*)(wb + 0);
  unsigned short* eWihB = (unsigned short*)(wb + (512ull << 10));
  unsigned short* dWihB = (unsigned short*)(wb + (1ull << 20));
  unsigned short* eWhhB = (unsigned short*)(wb + (2ull << 20));
  unsigned short* dWhhB = (unsigned short*)(wb + (4ull << 20));
  unsigned short* outWB = (unsigned short*)(wb + (6ull << 20));
  unsigned short* projE = (unsigned short*)(wb + (7ull << 20));
  unsigned short* projD = (unsigned short*)(wb + (8ull << 20));
  float* logits = (float*)d_out;

  cvt_kernel<<<128, 256, 0, stream>>>(emb, embB, 512 * 256);
  cvt_kernel<<<256, 256, 0, stream>>>(encWih, eWihB, 1024 * 256);
  cvt_kernel<<<256, 256, 0, stream>>>(decWih, dWihB, 1024 * 256);
  cvt_kernel<<<1024, 256, 0, stream>>>(encWhh, eWhhB, 1024 * 1024);
  cvt_kernel<<<1024, 256, 0, stream>>>(decWhh, dWhhB, 1024 * 1024);
  cvt_kernel<<<512, 256, 0, stream>>>(outW, outWB, 512 * 1024);

  // projected-vocab tables: proj[v] = emb[v] @ Wih^T + bih + bhh  (512x1024)
  gemm_bt_kernel<<<128, 256, 0, stream>>>(embB, 0, eWihB, encBih, encBhh,
                                          projE, nullptr, 256, 1024, 16);
  gemm_bt_kernel<<<128, 256, 0, stream>>>(embB, 0, dWihB, decBih, decBhh,
                                          projD, nullptr, 256, 1024, 16);

  rnn_scan5_kernel<<<128, 256, 0, stream>>>(eWhhB, dWhhB, projE, projD,
                                            decBih, decBhh, inputs, outputs,
                                            win, states);

  gemm_bt_kernel<<<4096, 256, 0, stream>>>(states, 3, outWB, nullptr, nullptr,
                                           nullptr, logits, 1024, 512, 8);
  logsoftmax_kernel<<<8192, 256, 0, stream>>>(logits, outB);
}

// Round 4
// 1830.218 us; speedup vs baseline: 1.3409x; 1.1085x over previous
//
#include <hip/hip_runtime.h>

// ---------------------------------------------------------------------------
// S2S RNN (encoder/decoder Elman + output log-softmax) on MI355X.
// fp32 in/out, bf16 operands + fp32 accumulate internally.
//
// Round-10: request-rate attack on the handshake sweep.
// Round-9 counters: FETCH=116MB = 232KB/step = one 32KB h-image x 8 groups
// refetched per step (producer stores invalidate, consumers refill) -> the
// latency story is fine; the cost is the POLL SWEEP issuing 65K 8B coherent
// loads per group-step (16x amplification at minimum width). Fix:
//   - 16B coherent polls: inline-asm global_load_dwordx4 sc0 sc1 (the same
//     L1/L2-bypass flags atomic codegen uses). Poison-validity per short
//     makes non-atomic 16B reads safe (old value is always poison).
//   - 8 WGs x 512 threads per group (was 16x256): each WG owns 128 cols,
//     8 waves; total sweep traffic per group-step halves (256KB), skew tail
//     has 8 participants. Thread stages ONE contiguous 64B chunk = 4 asm
//     loads from exactly one producer WG (clean early-exit).
// Kept from round-9: IC-hot 8-slot window, register-carried own slice,
// re-poison slot s-2, 0xAAAA->0xAAAB fixup, NT states stream, raw
// lgkm-only step barrier. ws need ~75 MB.
// ---------------------------------------------------------------------------

typedef short short8 __attribute__((ext_vector_type(8)));
typedef float floatx4 __attribute__((ext_vector_type(4)));
typedef unsigned int uint4v __attribute__((ext_vector_type(4)));

// ---- ws layout (~75 MB) ----
#define WS_WIN    0ull                        // 2 MB: [8][128][1024] bf16 window
#define WS_STATES (2ull << 20)                // 64 MB: [256][128][1024] bf16
#define WS_WB     (66ull << 20)               // weights/proj region

#define HS_STRIDE 1032  // shorts per LDS row (16B-aligned, +16B pad)

__device__ __forceinline__ float bf2f(unsigned short u) {
  union { unsigned u; float f; } x; x.u = ((unsigned)u) << 16; return x.f;
}
__device__ __forceinline__ unsigned short f2bf(float f) {
  union { float f; unsigned u; } x; x.f = f;
  unsigned r = x.u + 0x7FFFu + ((x.u >> 16) & 1u);  // RNE
  return (unsigned short)(r >> 16);
}
__device__ __forceinline__ unsigned pkminu16(unsigned a, unsigned b) {
  unsigned d;
  asm("v_pk_min_u16 %0, %1, %2" : "=v"(d) : "v"(a), "v"(b));
  return d;
}

// fp32 -> bf16 bulk convert, 4 elems/thread. n multiple of 1024.
__global__ __launch_bounds__(256) void cvt_kernel(
    const float* __restrict__ src, unsigned short* __restrict__ dst, int n)
{
  const int i = (blockIdx.x * 256 + threadIdx.x) * 4;
  if (i >= n) return;
  const float4 v = *(const float4*)(src + i);
  unsigned short o[4] = {f2bf(v.x), f2bf(v.y), f2bf(v.z), f2bf(v.w)};
  *(uint2*)(dst + i) = *(const uint2*)o;
}

// ---------------------------------------------------------------------------
// C[M,N] = gather(A)[M,K] . B[N,K]^T (+ fp32 bias), bf16 operands, fp32 acc.
// 64x64 WG tile, 4 waves, wave tile 16x64 via 16x16x32 bf16 MFMA.
// mode 0: dense rows.
// mode 3: A row m -> Abase + ((m&255)*128 + (m>>8)) * 1024  ([t][b][j] states)
// ---------------------------------------------------------------------------
__global__ __launch_bounds__(256) void gemm_bt_kernel(
    const unsigned short* __restrict__ Abase,
    const int mode,
    const unsigned short* __restrict__ Bmat,
    const float* __restrict__ bias0,
    const float* __restrict__ bias1,
    unsigned short* __restrict__ outp_bf,
    float* __restrict__ outp_f,
    const int K, const int N, const int nbn)
{
  __shared__ unsigned short As[64][264];
  __shared__ unsigned short Bs[64][264];
  __shared__ const unsigned short* rowsrc[64];

  const int tid = threadIdx.x;
  const int lane = tid & 63;
  const int wave = tid >> 6;
  const int bn = blockIdx.x % nbn;
  const int bm = blockIdx.x / nbn;
  const int m0 = bm * 64;
  const int j0 = bn * 64;

  if (tid < 64) {
    const int m = m0 + tid;
    const unsigned short* src;
    if (mode == 0) {
      src = Abase + (size_t)m * K;
    } else {  // mode 3
      src = Abase + ((size_t)(m & 255) * 128 + (m >> 8)) * 1024;
    }
    rowsrc[tid] = src;
  }

  const floatx4 zf = {0.f, 0.f, 0.f, 0.f};
  floatx4 acc0 = zf, acc1 = zf, acc2 = zf, acc3 = zf;

  for (int kc = 0; kc < K; kc += 256) {
    __syncthreads();
#pragma unroll
    for (int i = 0; i < 8; ++i) {
      const int idx = i * 256 + tid;
      const int r = idx >> 5;
      const int c = idx & 31;
      const unsigned short* s = rowsrc[r];
      *(short8*)&As[r][c * 8] = *(const short8*)(s + kc + c * 8);
      *(short8*)&Bs[r][c * 8] =
          *(const short8*)(Bmat + (size_t)(j0 + r) * K + kc + c * 8);
    }
    __syncthreads();
    const int ar = 16 * wave + (lane & 15);
    const int kq = (lane >> 4) * 8;
#pragma unroll
    for (int kk = 0; kk < 8; ++kk) {
      const short8 a = *(const short8*)&As[ar][kk * 32 + kq];
      const short8 bv0 = *(const short8*)&Bs[(lane & 15)][kk * 32 + kq];
      acc0 = __builtin_amdgcn_mfma_f32_16x16x32_bf16(a, bv0, acc0, 0, 0, 0);
      const short8 bv1 = *(const short8*)&Bs[16 + (lane & 15)][kk * 32 + kq];
      acc1 = __builtin_amdgcn_mfma_f32_16x16x32_bf16(a, bv1, acc1, 0, 0, 0);
      const short8 bv2 = *(const short8*)&Bs[32 + (lane & 15)][kk * 32 + kq];
      acc2 = __builtin_amdgcn_mfma_f32_16x16x32_bf16(a, bv2, acc2, 0, 0, 0);
      const short8 bv3 = *(const short8*)&Bs[48 + (lane & 15)][kk * 32 + kq];
      acc3 = __builtin_amdgcn_mfma_f32_16x16x32_bf16(a, bv3, acc3, 0, 0, 0);
    }
  }

  float bs[4] = {0.f, 0.f, 0.f, 0.f};
  if (bias0) {
#pragma unroll
    for (int nt = 0; nt < 4; ++nt) {
      const int jj = j0 + nt * 16 + (lane & 15);
      bs[nt] = bias0[jj] + bias1[jj];
    }
  }
  __syncthreads();
  const int rbase = 16 * wave + (lane >> 4) * 4;
  const int cl = lane & 15;

  if (outp_bf) {
#pragma unroll
    for (int i = 0; i < 4; ++i) {
      As[rbase + i][cl]      = f2bf(acc0[i] + bs[0]);
      As[rbase + i][16 + cl] = f2bf(acc1[i] + bs[1]);
      As[rbase + i][32 + cl] = f2bf(acc2[i] + bs[2]);
      As[rbase + i][48 + cl] = f2bf(acc3[i] + bs[3]);
    }
    __syncthreads();
#pragma unroll
    for (int i = 0; i < 2; ++i) {
      const int idx = i * 256 + tid;
      const int r = idx >> 3;
      const int c = idx & 7;
      *(short8*)(outp_bf + (size_t)(m0 + r) * N + j0 + c * 8) =
          *(const short8*)&As[r][c * 8];
    }
  } else {
    float (*Asf)[66] = (float(*)[66]) & As[0][0];
#pragma unroll
    for (int i = 0; i < 4; ++i) {
      Asf[rbase + i][cl]      = acc0[i] + bs[0];
      Asf[rbase + i][16 + cl] = acc1[i] + bs[1];
      Asf[rbase + i][32 + cl] = acc2[i] + bs[2];
      Asf[rbase + i][48 + cl] = acc3[i] + bs[3];
    }
    __syncthreads();
#pragma unroll
    for (int i = 0; i < 4; ++i) {
      const int idx = i * 256 + tid;
      const int r = idx >> 4;
      const int c = idx & 15;
      *(float4*)(outp_f + (size_t)(m0 + r) * N + j0 + c * 4) =
          *(const float4*)&Asf[r][c * 4];
    }
  }
}

// ---------------------------------------------------------------------------
// Round-10 recurrence. 64 WGs x 512 thr; group g = blockIdx&7 owns batch rows
// [16g,16g+16); 8 WGs/group cover 1024 cols (128/WG, 16/wave, 8 waves).
// IC-hot 8-slot window, per-thread 64B-chunk data-poll via 16B sc0sc1 loads.
// ---------------------------------------------------------------------------
__global__ __launch_bounds__(512) void rnn_scan6_kernel(
    const unsigned short* __restrict__ WhhE,
    const unsigned short* __restrict__ WhhD,
    const unsigned short* __restrict__ projE,
    const unsigned short* __restrict__ projD,
    const float* __restrict__ decBih,
    const float* __restrict__ decBhh,
    const int* __restrict__ intoks,     // inputs  [128][256] int32
    const int* __restrict__ outtoks,    // outputs [128][256] int32
    unsigned short* __restrict__ win,   // [8][128][1024] window slots
    unsigned short* __restrict__ states)// [256][128][1024] decoder states
{
  __shared__ unsigned short hs[2 * 16 * HS_STRIDE];  // double-buffered
  __shared__ int toks[16 * 257];

  const int tid = threadIdx.x;
  const int lane = tid & 63;
  const int wave = tid >> 6;                   // 0..7
  const int g = blockIdx.x & 7;
  const int slot = blockIdx.x >> 3;            // 0..7
  const int b0 = g * 16;
  const int q = lane >> 4;
  const int cl = lane & 15;
  const int jwb = slot * 128 + wave * 16;      // wave's 16-column base
  const int jq4 = jwb + q * 4;                 // this thread's 4 output columns
  // Staging: thread tid handles 64B chunk (row prow, cols pc32..pc32+31),
  // produced by WG (chunkcol>>2) of this group. Own WG's data stays in obp.
  const int prow = tid >> 5;                   // 0..15
  const int pcc = tid & 31;                    // col-chunk 0..31 (32 cols each)
  const int pc32 = pcc * 32;
  const bool own = ((pcc >> 2) == slot);

  short8 w[32];  // Whh[jwb+cl][0:1024] A-fragments — 128 VGPRs
  const floatx4 zf = {0.f, 0.f, 0.f, 0.f};
  unsigned long long obp = 0;  // packed own h(s-1): row b0+cl, cols jq4..+3
  const size_t prodoff = (size_t)(b0 + cl) * 1024 + jq4;

  for (int phase = 0; phase < 2; ++phase) {
    const unsigned short* Whh = phase ? WhhD : WhhE;
    const unsigned short* proj = phase ? projD : projE;
    const int* gt = phase ? outtoks : intoks;
    {
      const unsigned short* wp = Whh + (size_t)(jwb + cl) * 1024 + q * 8;
#pragma unroll
      for (int kk = 0; kk < 32; ++kk) w[kk] = *(const short8*)(wp + kk * 32);
    }
    float xb[4] = {0.f, 0.f, 0.f, 0.f};
    if (phase) {  // decoder t==0 input is zero -> xp = bih+bhh (fp32, exact)
#pragma unroll
      for (int i = 0; i < 4; ++i) xb[i] = decBih[jq4 + i] + decBhh[jq4 + i];
    }
    // stage this phase's token ids (16 rows x 256 steps) into LDS
    __syncthreads();
#pragma unroll
    for (int i = 0; i < 8; ++i) {
      const int idx = i * 512 + tid;
      toks[(idx >> 8) * 257 + (idx & 255)] =
          gt[(size_t)(b0 + (idx >> 8)) * 256 + (idx & 255)];
    }
    __syncthreads();

    for (int t = 0; t < 256; ++t) {
      const int s = phase * 256 + t;
      // xp gather (issued early; latency hides under the h poll)
      float xpf[4];
      {
        const int tt = phase ? (t > 0 ? t - 1 : 0) : t;
        const int tok = toks[cl * 257 + tt];
        const uint2 xr = *(const uint2*)(proj + (size_t)tok * 1024 + jq4);
        const unsigned short* xs = (const unsigned short*)&xr;
#pragma unroll
        for (int i = 0; i < 4; ++i) xpf[i] = bf2f(xs[i]);
        if (phase && t == 0) {
#pragma unroll
          for (int i = 0; i < 4; ++i) xpf[i] = xb[i];
        }
      }

      unsigned short* hsb = hs + (s & 1) * (16 * HS_STRIDE);
      if (s > 0) {
        const unsigned short* hprev =
            win + (size_t)((s - 1) & 7) * 131072 + b0 * 1024;
        if (!own) {
          const unsigned long long paddr =
              (unsigned long long)(hprev + prow * 1024 + pc32);
          uint4v d0, d1, d2, d3;
          for (;;) {
            // 4x 16B coherent loads (L1+L2 bypass) of one 64B chunk, all in
            // flight together, one wait. volatile: must re-issue per retry.
            asm volatile(
                "global_load_dwordx4 %0, %4, off sc0 sc1\n\t"
                "global_load_dwordx4 %1, %4, off offset:16 sc0 sc1\n\t"
                "global_load_dwordx4 %2, %4, off offset:32 sc0 sc1\n\t"
                "global_load_dwordx4 %3, %4, off offset:48 sc0 sc1\n\t"
                "s_waitcnt vmcnt(0)"
                : "=&v"(d0), "=&v"(d1), "=&v"(d2), "=&v"(d3)
                : "v"(paddr)
                : "memory");
            // poison-validity: any short == 0xAAAA -> producer not done yet
            unsigned m0v = 0xFFFFFFFFu, m1v = 0xFFFFFFFFu;
            unsigned m2v = 0xFFFFFFFFu, m3v = 0xFFFFFFFFu;
#pragma unroll
            for (int i = 0; i < 4; ++i) {
              m0v = pkminu16(m0v, d0[i] ^ 0xAAAAAAAAu);
              m1v = pkminu16(m1v, d1[i] ^ 0xAAAAAAAAu);
              m2v = pkminu16(m2v, d2[i] ^ 0xAAAAAAAAu);
              m3v = pkminu16(m3v, d3[i] ^ 0xAAAAAAAAu);
            }
            const unsigned mm = pkminu16(pkminu16(m0v, m1v), pkminu16(m2v, m3v));
            const unsigned hz = (mm - 0x00010001u) & ~mm & 0x80008000u;
            if (hz == 0u) break;
            __builtin_amdgcn_s_sleep(1);
          }
          // stage the 64B chunk
          unsigned short* dst = &hsb[prow * HS_STRIDE + pc32];
          *(uint4v*)(dst + 0)  = d0;
          *(uint4v*)(dst + 8)  = d1;
          *(uint4v*)(dst + 16) = d2;
          *(uint4v*)(dst + 24) = d3;
        }
        // own slice straight from registers (no memory round-trip)
        *(unsigned long long*)&hsb[cl * HS_STRIDE + jq4] = obp;
      }
      // Raw barrier: drain LDS writes only; window/states/poison stores stay
      // in flight (never vmcnt-drained on the critical path).
      __builtin_amdgcn_sched_barrier(0);
      asm volatile("s_waitcnt lgkmcnt(0)" ::: "memory");
      __builtin_amdgcn_s_barrier();
      __builtin_amdgcn_sched_barrier(0);

      floatx4 acc0 = zf, acc1 = zf, acc2 = zf, acc3 = zf;
      if (s > 0) {
        // swapped operands: D[j_local][b_local]; thread owns (b0+cl, jq4..+3)
        const unsigned short* hrow = &hsb[cl * HS_STRIDE + q * 8];
#pragma unroll
        for (int kk = 0; kk < 32; kk += 4) {
          const short8 a0 = *(const short8*)(hrow + (kk + 0) * 32);
          const short8 a1 = *(const short8*)(hrow + (kk + 1) * 32);
          const short8 a2 = *(const short8*)(hrow + (kk + 2) * 32);
          const short8 a3 = *(const short8*)(hrow + (kk + 3) * 32);
          acc0 = __builtin_amdgcn_mfma_f32_16x16x32_bf16(w[kk + 0], a0, acc0, 0, 0, 0);
          acc1 = __builtin_amdgcn_mfma_f32_16x16x32_bf16(w[kk + 1], a1, acc1, 0, 0, 0);
          acc2 = __builtin_amdgcn_mfma_f32_16x16x32_bf16(w[kk + 2], a2, acc2, 0, 0, 0);
          acc3 = __builtin_amdgcn_mfma_f32_16x16x32_bf16(w[kk + 3], a3, acc3, 0, 0, 0);
        }
      }
      unsigned short ob[4];
#pragma unroll
      for (int i = 0; i < 4; ++i) {
        const float pre = acc0[i] + acc1[i] + acc2[i] + acc3[i] + xpf[i];
        const float e = __expf(2.f * pre);
        ob[i] = f2bf(1.f - 2.f / (e + 1.f));  // tanh
        if (ob[i] == 0xAAAAu) ob[i] = 0xAAABu;  // anti-hang: 1-ulp fixup
      }
      obp = *(const unsigned long long*)ob;
      // window store first (critical handshake), IC-hot line.
      __hip_atomic_store(
          (unsigned long long*)(win + (size_t)(s & 7) * 131072 + prodoff),
          obp, __ATOMIC_RELAXED, __HIP_MEMORY_SCOPE_AGENT);
      // decoder states stream: nontemporal, background (never drained here).
      if (phase) {
        __builtin_nontemporal_store(
            obp, (unsigned long long*)(states + (size_t)t * 131072 + prodoff));
      }
      // re-poison slot s-2 (post-barrier => all peers consumed it; retires
      // >=5 steps before reuse at s+6).
      if (s >= 2) {
        __hip_atomic_store(
            (unsigned long long*)(win + (size_t)((s - 2) & 7) * 131072 + prodoff),
            0xAAAAAAAAAAAAAAAAull, __ATOMIC_RELAXED, __HIP_MEMORY_SCOPE_AGENT);
      }
    }
  }
}

// ---------------------------------------------------------------------------
// Rowwise log_softmax over V=512 with fp32 bias, fp32 in-place on d_out.
// ---------------------------------------------------------------------------
__global__ __launch_bounds__(256) void logsoftmax_kernel(
    float* __restrict__ logits, const float* __restrict__ outb)
{
  const int row = blockIdx.x * 4 + (threadIdx.x >> 6);
  const int lane = threadIdx.x & 63;
  float* rp = logits + (size_t)row * 512 + lane * 8;
  const float4 a0 = *(const float4*)rp;
  const float4 a1 = *(const float4*)(rp + 4);
  const float4 b0 = *(const float4*)(outb + lane * 8);
  const float4 b1 = *(const float4*)(outb + lane * 8 + 4);
  float v[8] = {a0.x + b0.x, a0.y + b0.y, a0.z + b0.z, a0.w + b0.w,
                a1.x + b1.x, a1.y + b1.y, a1.z + b1.z, a1.w + b1.w};
  float mx = v[0];
#pragma unroll
  for (int i = 1; i < 8; ++i) mx = fmaxf(mx, v[i]);
#pragma unroll
  for (int m = 1; m < 64; m <<= 1) mx = fmaxf(mx, __shfl_xor(mx, m, 64));
  float sum = 0.f;
#pragma unroll
  for (int i = 0; i < 8; ++i) sum += __expf(v[i] - mx);
#pragma unroll
  for (int m = 1; m < 64; m <<= 1) sum += __shfl_xor(sum, m, 64);
  const float lse = mx + __logf(sum);
  float4 o0 = {v[0] - lse, v[1] - lse, v[2] - lse, v[3] - lse};
  float4 o1 = {v[4] - lse, v[5] - lse, v[6] - lse, v[7] - lse};
  *(float4*)rp = o0;
  *(float4*)(rp + 4) = o1;
}

extern "C" void kernel_launch(void* const* d_in, const int* in_sizes, int n_in,
                              void* d_out, int out_size, void* d_ws, size_t ws_size,
                              hipStream_t stream)
{
  const int* inputs  = (const int*)d_in[0];
  const int* outputs = (const int*)d_in[1];
  const float* emb    = (const float*)d_in[2];
  const float* encWih = (const float*)d_in[3];
  const float* encWhh = (const float*)d_in[4];
  const float* encBih = (const float*)d_in[5];
  const float* encBhh = (const float*)d_in[6];
  const float* decWih = (const float*)d_in[7];
  const float* decWhh = (const float*)d_in[8];
  const float* decBih = (const float*)d_in[9];
  const float* decBhh = (const float*)d_in[10];
  const float* outW   = (const float*)d_in[11];
  const float* outB   = (const float*)d_in[12];

  char* ws = (char*)d_ws;
  unsigned short* win    = (unsigned short*)(ws + WS_WIN);
  unsigned short* states = (unsigned short*)(ws + WS_STATES);
  char* wb = ws + WS_WB;
  unsigned short* embB  = (unsigned short*)(wb + 0);
  unsigned short* eWihB = (unsigned short*)(wb + (512ull << 10));
  unsigned short* dWihB = (unsigned short*)(wb + (1ull << 20));
  unsigned short* eWhhB = (unsigned short*)(wb + (2ull << 20));
  unsigned short* dWhhB = (unsigned short*)(wb + (4ull << 20));
  unsigned short* outWB = (unsigned short*)(wb + (6ull << 20));
  unsigned short* projE = (unsigned short*)(wb + (7ull << 20));
  unsigned short* projD = (unsigned short*)(wb + (8ull << 20));
  float* logits = (float*)d_out;

  cvt_kernel<<<128, 256, 0, stream>>>(emb, embB, 512 * 256);
  cvt_kernel<<<256, 256, 0, stream>>>(encWih, eWihB, 1024 * 256);
  cvt_kernel<<<256, 256, 0, stream>>>(decWih, dWihB, 1024 * 256);
  cvt_kernel<<<1024, 256, 0, stream>>>(encWhh, eWhhB, 1024 * 1024);
  cvt_kernel<<<1024, 256, 0, stream>>>(decWhh, dWhhB, 1024 * 1024);
  cvt_kernel<<<512, 256, 0, stream>>>(outW, outWB, 512 * 1024);

  // projected-vocab tables: proj[v] = emb[v] @ Wih^T + bih + bhh  (512x1024)
  gemm_bt_kernel<<<128, 256, 0, stream>>>(embB, 0, eWihB, encBih, encBhh,
                                          projE, nullptr, 256, 1024, 16);
  gemm_bt_kernel<<<128, 256, 0, stream>>>(embB, 0, dWihB, decBih, decBhh,
                                          projD, nullptr, 256, 1024, 16);

  rnn_scan6_kernel<<<64, 512, 0, stream>>>(eWhhB, dWhhB, projE, projD,
                                           decBih, decBhh, inputs, outputs,
                                           win, states);

  gemm_bt_kernel<<<4096, 256, 0, stream>>>(states, 3, outWB, nullptr, nullptr,
                                           nullptr, logits, 1024, 512, 8);
  logsoftmax_kernel<<<8192, 256, 0, stream>>>(logits, outB);
}